// Round 6
// baseline (591.123 us; speedup 1.0000x reference)
//
#include <hip/hip_runtime.h>
#include <hip/hip_bf16.h>
#include <float.h>

// Problem constants (fixed by the reference)
constexpr int NENT  = 100000;
constexpr int DDIM  = 256;
constexpr int BQ    = 64;
constexpr int CANDN = 10000;
constexpr int KTOP  = 10;
constexpr int NSLICE = 16;
constexpr int SLICE  = 6272;    // 16*6272 = 100352 >= NENT, multiple of 4
constexpr int HPAD   = 132;     // histG per-(b,s) stride

typedef short v8s __attribute__((ext_vector_type(8)));   // 8 bf16 (4 VGPRs)
typedef float v4f __attribute__((ext_vector_type(4)));   // MFMA accumulator

// 3-way split: x ~= b0 + b1 + b2 (bf16 each), residual ~2^-21 |x|
__device__ inline void split3(float x, unsigned short& h0, unsigned short& h1,
                              unsigned short& h2) {
    unsigned t0 = __float_as_uint(x) & 0xffff0000u;
    float r1 = x - __uint_as_float(t0);
    unsigned t1 = __float_as_uint(r1) & 0xffff0000u;
    float r2 = r1 - __uint_as_float(t1);
    h0 = (unsigned short)(t0 >> 16);
    h1 = (unsigned short)(t1 >> 16);
    h2 = (unsigned short)(__float_as_uint(r2) >> 16);
}

// split 8 contiguous fp32 (LDS) into three bf16x8 fragments
__device__ inline void split8(const float* ap, v8s& o0, v8s& o1, v8s& o2) {
    union { v8s v; unsigned short u[8]; } r0, r1, r2;
    float4 f0 = *(const float4*)ap;
    float4 f1 = *(const float4*)(ap + 4);
    float av[8] = {f0.x, f0.y, f0.z, f0.w, f1.x, f1.y, f1.z, f1.w};
    #pragma unroll
    for (int j = 0; j < 8; j++)
        split3(av[j], r0.u[j], r1.u[j], r2.u[j]);
    o0 = r0.v; o1 = r1.v; o2 = r2.v;
}

// ---------------------------------------------------------------------------
// K1: targets (stored transposed [d][b]) + query hash codes (packed 4x u32)
// ---------------------------------------------------------------------------
__global__ __launch_bounds__(128) void k_targets(
    const int* __restrict__ head, const int* __restrict__ rel,
    const float* __restrict__ E, const float* __restrict__ Rm,
    const float* __restrict__ proj,
    float* __restrict__ tgtT, unsigned* __restrict__ thash)
{
    __shared__ float tg[DDIM];
    int b = blockIdx.x;
    int tid = threadIdx.x;
    int h = head[b], r = rel[b];
    for (int d = tid; d < DDIM; d += 128) {
        float v = E[h*DDIM + d] * Rm[r*DDIM + d];
        tg[d] = v;
        tgtT[d*BQ + b] = v;
    }
    __syncthreads();
    int t = tid >> 5, hh = tid & 31;
    float acc = 0.f;
    #pragma unroll 8
    for (int d = 0; d < DDIM; d++)
        acc += tg[d] * proj[(t*DDIM + d)*32 + hh];
    unsigned long long m = __ballot(acc > 0.0f);
    int lane = tid & 63, w = tid >> 6;
    if (lane == 0) {
        thash[b*4 + w*2 + 0] = (unsigned)(m & 0xffffffffull);
        thash[b*4 + w*2 + 1] = (unsigned)(m >> 32);
    }
}

// ---------------------------------------------------------------------------
// K1b: build W = [proj cols | targets], 3-way split bf16 planes, layout [c][d].
// ---------------------------------------------------------------------------
__global__ __launch_bounds__(256) void k_prepw(
    const float* __restrict__ proj, const float* __restrict__ tgtT,
    unsigned short* __restrict__ Whi, unsigned short* __restrict__ Wmid,
    unsigned short* __restrict__ Wlo)
{
    int c = blockIdx.x;
    int d = threadIdx.x;   // DDIM == 256
    float x = (c < 128) ? proj[((c >> 5)*DDIM + d)*32 + (c & 31)]
                        : tgtT[d*BQ + (c - 128)];
    unsigned short h0, h1, h2;
    split3(x, h0, h1, h2);
    Whi [c*DDIM + d] = h0;
    Wmid[c*DDIM + d] = h1;
    Wlo [c*DDIM + d] = h2;
}

// ---------------------------------------------------------------------------
// K2: MFMA bf16x3 (6-product) GEMM.  out[n][c] = sum_d E[n][d] * W[c][d]
//   cols 0..127 -> sign bits packed to ahash[n][4]; cols 128..191 -> scores.
// Block: 256 thr = 2x2 waves; tile 128 rows x 192 cols; K-chunks of 32.
// A staged as fp32 in LDS (per-lane split at use); B staged pre-split (3 planes).
// ---------------------------------------------------------------------------
constexpr int TILE_E = 128;
constexpr int LSTR = 40;         // B plane halfword stride (32 + 8 pad)
constexpr int ASTR = 36;         // A fp32 float stride (32 + 4 pad)

__global__ __launch_bounds__(256, 2) void k_gemm(
    const float* __restrict__ E,
    const unsigned short* __restrict__ Whi, const unsigned short* __restrict__ Wmid,
    const unsigned short* __restrict__ Wlo,
    unsigned* __restrict__ ahash, float* __restrict__ scores)
{
    __shared__ __align__(16) float Af[TILE_E*ASTR];             // 18432 B
    __shared__ __align__(16) unsigned short Bhi[192*LSTR];      // 15360 B
    __shared__ __align__(16) unsigned short Bmid[192*LSTR];     // 15360 B
    __shared__ __align__(16) unsigned short Blo[192*LSTR];      // 15360 B
    unsigned short* bitsHalf = (unsigned short*)Af;             // aliased after compute

    int tid = threadIdx.x;
    int l = tid & 63, w = tid >> 6;
    int wm = w >> 1, wn = w & 1;
    int m = l & 15, quad = l >> 4;
    int n0 = blockIdx.x * TILE_E;

    v4f acc[4][6];
    #pragma unroll
    for (int a = 0; a < 4; a++)
        #pragma unroll
        for (int c = 0; c < 6; c++)
            acc[a][c] = (v4f)0.0f;

    for (int ch = 0; ch < DDIM/32; ch++) {
        int d0 = ch * 32;
        __syncthreads();
        // ---- stage A chunk fp32 (128x32) ----
        #pragma unroll
        for (int it = 0; it < 4; it++) {
            int idx = tid + it*256;         // 0..1023
            int row = idx >> 3;
            int kq  = (idx & 7) * 4;
            int n = n0 + row; if (n >= NENT) n = NENT - 1;
            *(float4*)&Af[row*ASTR + kq] = *(const float4*)(E + (size_t)n*DDIM + d0 + kq);
        }
        // ---- stage B chunk (192x32), 3 pre-split planes ----
        #pragma unroll
        for (int it = 0; it < 3; it++) {
            int idx = tid + it*256;         // 0..767
            int col = idx >> 2;
            int k8  = (idx & 3) * 8;
            *(uint4*)&Bhi [col*LSTR + k8] = *(const uint4*)(Whi  + col*DDIM + d0 + k8);
            *(uint4*)&Bmid[col*LSTR + k8] = *(const uint4*)(Wmid + col*DDIM + d0 + k8);
            *(uint4*)&Blo [col*LSTR + k8] = *(const uint4*)(Wlo  + col*DDIM + d0 + k8);
        }
        __syncthreads();
        // ---- A fragments: fp32 from LDS, split in-register ----
        v8s a0[4], a1[4], a2[4];
        #pragma unroll
        for (int a = 0; a < 4; a++)
            split8(&Af[(wm*64 + a*16 + m)*ASTR + quad*8], a0[a], a1[a], a2[a]);
        // ---- 6-product MFMA ----
        #pragma unroll
        for (int c = 0; c < 6; c++) {
            int co = (wn*96 + c*16 + m)*LSTR + quad*8;
            v8s b0 = *(const v8s*)&Bhi [co];
            v8s b1 = *(const v8s*)&Bmid[co];
            v8s b2 = *(const v8s*)&Blo [co];
            #pragma unroll
            for (int a = 0; a < 4; a++) {
                acc[a][c] = __builtin_amdgcn_mfma_f32_16x16x32_bf16(a2[a], b0, acc[a][c], 0, 0, 0);
                acc[a][c] = __builtin_amdgcn_mfma_f32_16x16x32_bf16(a0[a], b2, acc[a][c], 0, 0, 0);
                acc[a][c] = __builtin_amdgcn_mfma_f32_16x16x32_bf16(a1[a], b1, acc[a][c], 0, 0, 0);
                acc[a][c] = __builtin_amdgcn_mfma_f32_16x16x32_bf16(a1[a], b0, acc[a][c], 0, 0, 0);
                acc[a][c] = __builtin_amdgcn_mfma_f32_16x16x32_bf16(a0[a], b1, acc[a][c], 0, 0, 0);
                acc[a][c] = __builtin_amdgcn_mfma_f32_16x16x32_bf16(a0[a], b0, acc[a][c], 0, 0, 0);
            }
        }
    }

    __syncthreads();   // protect Af before bitsHalf aliasing
    // ---- epilogue: C/D layout col=lane&15, row=quad*4+reg ----
    #pragma unroll
    for (int c = 0; c < 6; c++) {
        int ct = wn*6 + c;                 // global col-tile 0..11
        if (ct < 8) {
            #pragma unroll
            for (int a = 0; a < 4; a++) {
                #pragma unroll
                for (int r = 0; r < 4; r++) {
                    unsigned long long mb = __ballot(acc[a][c][r] > 0.0f);
                    if (m == 0) {
                        int rowl = wm*64 + a*16 + quad*4 + r;
                        bitsHalf[rowl*8 + ct] = (unsigned short)(mb >> (quad*16));
                    }
                }
            }
        } else {
            int b = ct*16 - 128 + m;       // query index 0..63
            #pragma unroll
            for (int a = 0; a < 4; a++) {
                int nb = n0 + wm*64 + a*16 + quad*4;
                if (nb < NENT)
                    *(float4*)(scores + (size_t)b*NENT + nb) = *(float4*)&acc[a][c];
            }
        }
    }
    __syncthreads();
    if (tid < TILE_E) {
        int n = n0 + tid;
        if (n < NENT)
            *(uint4*)(ahash + (size_t)n*4) = *(const uint4*)&bitsHalf[tid*8];
    }
}

// ---------------------------------------------------------------------------
// K3a: per-(query,slice) distance bytes + slice histogram.
// ---------------------------------------------------------------------------
__global__ __launch_bounds__(256) void k_dist(
    const unsigned* __restrict__ ahash, const unsigned* __restrict__ thash,
    unsigned char* __restrict__ dist8, unsigned short* __restrict__ histG)
{
    __shared__ unsigned hist[HPAD];
    int s = blockIdx.x, b = blockIdx.y, tid = threadIdx.x;
    for (int i = tid; i < HPAD; i += 256) hist[i] = 0u;
    uint4 tw = *(const uint4*)(thash + b*4);
    __syncthreads();
    int n0 = s*SLICE;
    int n1 = n0 + SLICE; if (n1 > NENT) n1 = NENT;
    unsigned char* drow = dist8 + (size_t)b*NENT;
    for (int n = n0 + tid*4; n < n1; n += 1024) {
        int dv[4];
        #pragma unroll
        for (int i = 0; i < 4; i++) {
            uint4 a = *(const uint4*)(ahash + (size_t)(n+i)*4);
            dv[i] = __popc(a.x^tw.x) + __popc(a.y^tw.y) +
                    __popc(a.z^tw.z) + __popc(a.w^tw.w);
            atomicAdd(&hist[dv[i]], 1u);
        }
        uchar4 o = make_uchar4((unsigned char)dv[0], (unsigned char)dv[1],
                               (unsigned char)dv[2], (unsigned char)dv[3]);
        *(uchar4*)(drow + n) = o;
    }
    __syncthreads();
    unsigned short* hrow = histG + ((size_t)b*NSLICE + s)*HPAD;
    for (int i = tid; i < 129; i += 256) hrow[i] = (unsigned short)hist[i];
}

// ---------------------------------------------------------------------------
// K3b: per-query: total histogram -> d*, quota R; slice prefix -> nCut.
// ---------------------------------------------------------------------------
__global__ __launch_bounds__(64) void k_cut(
    const unsigned char* __restrict__ dist8, const unsigned short* __restrict__ histG,
    int* __restrict__ dsG, int* __restrict__ ncG)
{
    __shared__ unsigned histT[HPAD];
    __shared__ int dsS, slS, rpS;
    int b = blockIdx.x, tid = threadIdx.x;
    for (int d = tid; d < 129; d += 64) {
        unsigned sum = 0;
        for (int s = 0; s < NSLICE; s++)
            sum += histG[((size_t)b*NSLICE + s)*HPAD + d];
        histT[d] = sum;
    }
    __syncthreads();
    if (tid == 0) {
        unsigned cum = 0; int ds = 128; unsigned R = 1;
        for (int d = 0; d < 129; d++) {
            unsigned c = cum + histT[d];
            if (c >= (unsigned)CANDN) { ds = d; R = (unsigned)CANDN - cum; break; }
            cum = c;
        }
        dsS = ds; dsG[b] = ds;
        unsigned acc = 0;
        for (int s = 0; s < NSLICE; s++) {
            unsigned c = histG[((size_t)b*NSLICE + s)*HPAD + ds];
            if (acc + c >= R) { slS = s; rpS = (int)(R - acc); break; }
            acc += c;
        }
    }
    __syncthreads();
    int ds = dsS;
    unsigned Rp = (unsigned)rpS;
    const unsigned char* drow = dist8 + (size_t)b*NENT;
    int sBase = slS*SLICE;
    int sEnd = sBase + SLICE; if (sEnd > NENT) sEnd = NENT;
    unsigned cnt = 0;
    for (int base = sBase; base < sEnd; base += 64) {
        int n = base + tid;
        bool eq = (n < sEnd) && (drow[n] == (unsigned char)ds);
        unsigned long long mm = __ballot(eq);
        unsigned c = __popcll(mm);
        if (cnt + c >= Rp) {
            unsigned pre = __popcll(mm & ((1ull << tid) - 1ull));
            if (eq && (cnt + pre + 1u == Rp)) ncG[b] = n;
            break;
        }
        cnt += c;
    }
}

// ---------------------------------------------------------------------------
// K4a: per-(query, slice) single-pass approximate top-10 (pool builder).
// ---------------------------------------------------------------------------
__global__ __launch_bounds__(256) void k_part(
    const unsigned char* __restrict__ dist8, const float* __restrict__ scores,
    const int* __restrict__ dsG, const int* __restrict__ ncG,
    float* __restrict__ partS, int* __restrict__ partI)
{
    __shared__ float rs[256];
    __shared__ int   ri[256];
    __shared__ int   rt[256];

    int s = blockIdx.x, b = blockIdx.y, tid = threadIdx.x;
    int ds = dsG[b], nc = ncG[b];
    const unsigned char* drow = dist8 + (size_t)b*NENT;
    const float* srow = scores + (size_t)b*NENT;
    int n0 = s*SLICE;
    int n1 = n0 + SLICE; if (n1 > NENT) n1 = NENT;

    float topS[KTOP]; int topI[KTOP];
    #pragma unroll
    for (int i = 0; i < KTOP; i++) { topS[i] = -FLT_MAX; topI[i] = 0x7fffffff; }

    for (int n = n0 + tid*4; n < n1; n += 1024) {
        uchar4 dv = *(const uchar4*)(drow + n);
        unsigned char da[4] = {dv.x, dv.y, dv.z, dv.w};
        #pragma unroll
        for (int i = 0; i < 4; i++) {
            int d = da[i];
            int nn = n + i;
            if (d < ds || (d == ds && nn <= nc)) {
                float sc = srow[nn];
                if (sc > topS[KTOP-1]) {
                    int p = KTOP - 1;
                    while (p > 0 && topS[p-1] < sc) {
                        topS[p] = topS[p-1]; topI[p] = topI[p-1]; p--;
                    }
                    topS[p] = sc; topI[p] = nn;
                }
            }
        }
    }

    int ph = 0;
    for (int r = 0; r < KTOP; r++) {
        rs[tid] = topS[ph]; ri[tid] = topI[ph]; rt[tid] = tid;
        __syncthreads();
        for (int st = 128; st > 0; st >>= 1) {
            if (tid < st) {
                bool take = (rs[tid+st] > rs[tid]) ||
                            (rs[tid+st] == rs[tid] && ri[tid+st] < ri[tid]);
                if (take) { rs[tid]=rs[tid+st]; ri[tid]=ri[tid+st]; rt[tid]=rt[tid+st]; }
            }
            __syncthreads();
        }
        if (tid == 0) {
            partS[((size_t)b*NSLICE + s)*KTOP + r] = rs[0];
            partI[((size_t)b*NSLICE + s)*KTOP + r] = ri[0];
        }
        int winner = rt[0];
        __syncthreads();
        if (tid == winner) ph++;
        __syncthreads();
    }
}

// ---------------------------------------------------------------------------
// K4b: exact fp32 rescoring of the 160-candidate pool + exact top-10.
// Sequential-d fp32 dot matches the passing R4 kernel's accumulation order.
// ---------------------------------------------------------------------------
__global__ __launch_bounds__(256) void k_merge(
    const int* __restrict__ partI, const float* __restrict__ tgtT,
    const float* __restrict__ E, float* __restrict__ out)
{
    __shared__ float tg[DDIM];
    __shared__ float sc2[NSLICE*KTOP];
    __shared__ int   ix2[NSLICE*KTOP];
    int b = blockIdx.x, tid = threadIdx.x;
    for (int d = tid; d < DDIM; d += 256) tg[d] = tgtT[d*BQ + b];
    __syncthreads();
    if (tid < NSLICE*KTOP) {
        int idx = partI[(size_t)b*NSLICE*KTOP + tid];
        float s = -FLT_MAX;
        if (idx >= 0 && idx < NENT) {
            const float* er = E + (size_t)idx*DDIM;
            float acc = 0.f;
            #pragma unroll 8
            for (int d = 0; d < DDIM; d++) acc += er[d] * tg[d];
            s = acc;
        }
        sc2[tid] = s; ix2[tid] = idx;
    }
    __syncthreads();
    if (tid == 0) {
        bool used[NSLICE*KTOP];
        for (int i = 0; i < NSLICE*KTOP; i++) used[i] = false;
        for (int r = 0; r < KTOP; r++) {
            float bs = -FLT_MAX; int bi = 0x7fffffff; int bp = -1;
            for (int i = 0; i < NSLICE*KTOP; i++) {
                if (!used[i]) {
                    float v = sc2[i]; int id = ix2[i];
                    if (v > bs || (v == bs && id < bi)) { bs = v; bi = id; bp = i; }
                }
            }
            used[bp] = true;
            out[b*KTOP + r]           = (float)bi;
            out[BQ*KTOP + b*KTOP + r] = bs;
        }
    }
}

// ---------------------------------------------------------------------------
extern "C" void kernel_launch(void* const* d_in, const int* in_sizes, int n_in,
                              void* d_out, int out_size, void* d_ws, size_t ws_size,
                              hipStream_t stream)
{
    const int*   head = (const int*)d_in[0];
    const int*   rel  = (const int*)d_in[1];
    const float* E    = (const float*)d_in[2];
    const float* Rm   = (const float*)d_in[3];
    const float* proj = (const float*)d_in[4];
    // d_in[5] = k (always 10)

    char* ws = (char*)d_ws;
    float*          tgtT   = (float*)(ws);                    // 65536 B
    unsigned*       thash  = (unsigned*)(ws + 65536);         // 1024 B
    unsigned*       ahash  = (unsigned*)(ws + 66560);         // 1.6 MB
    float*          scores = (float*)(ws + 1666560);          // 25.6 MB
    unsigned char*  dist8  = (unsigned char*)(ws + 27266560); // 6.4 MB
    int*            dsG    = (int*)(ws + 33666560);           // 256 B
    int*            ncG    = (int*)(ws + 33666816);           // 256 B
    float*          partS  = (float*)(ws + 33667072);         // 40960 B
    int*            partI  = (int*)(ws + 33708032);           // 40960 B
    unsigned short* histG  = (unsigned short*)(ws + 33748992);// 270336 B
    unsigned short* Whi    = (unsigned short*)(ws + 34019328);// 98304 B
    unsigned short* Wmid   = (unsigned short*)(ws + 34117632);// 98304 B
    unsigned short* Wlo    = (unsigned short*)(ws + 34215936);// 98304 B
    float*          out    = (float*)d_out;

    hipLaunchKernelGGL(k_targets, dim3(BQ), dim3(128), 0, stream,
                       head, rel, E, Rm, proj, tgtT, thash);
    hipLaunchKernelGGL(k_prepw, dim3(192), dim3(256), 0, stream,
                       proj, tgtT, Whi, Wmid, Wlo);
    hipLaunchKernelGGL(k_gemm, dim3((NENT + TILE_E - 1)/TILE_E), dim3(256), 0, stream,
                       E, Whi, Wmid, Wlo, ahash, scores);
    hipLaunchKernelGGL(k_dist, dim3(NSLICE, BQ), dim3(256), 0, stream,
                       ahash, thash, dist8, histG);
    hipLaunchKernelGGL(k_cut, dim3(BQ), dim3(64), 0, stream,
                       dist8, histG, dsG, ncG);
    hipLaunchKernelGGL(k_part, dim3(NSLICE, BQ), dim3(256), 0, stream,
                       dist8, scores, dsG, ncG, partS, partI);
    hipLaunchKernelGGL(k_merge, dim3(BQ), dim3(256), 0, stream,
                       partI, tgtT, E, out);
}

// Round 7
// 587.187 us; speedup vs baseline: 1.0067x; 1.0067x over previous
//
#include <hip/hip_runtime.h>
#include <hip/hip_bf16.h>
#include <float.h>

// Problem constants (fixed by the reference)
constexpr int NENT  = 100000;
constexpr int DDIM  = 256;
constexpr int BQ    = 64;
constexpr int CANDN = 10000;
constexpr int KTOP  = 10;
constexpr int NSLICE = 16;
constexpr int SLICE  = 6272;    // 16*6272 = 100352 >= NENT, multiple of 4
constexpr int HPAD   = 132;     // histG per-(b,s) stride

typedef short v8s __attribute__((ext_vector_type(8)));   // 8 bf16 (4 VGPRs)
typedef float v4f __attribute__((ext_vector_type(4)));   // MFMA accumulator

// 3-way split: x ~= b0 + b1 + b2 (bf16 each), residual ~2^-21 |x|
__device__ inline void split3(float x, unsigned short& h0, unsigned short& h1,
                              unsigned short& h2) {
    unsigned t0 = __float_as_uint(x) & 0xffff0000u;
    float r1 = x - __uint_as_float(t0);
    unsigned t1 = __float_as_uint(r1) & 0xffff0000u;
    float r2 = r1 - __uint_as_float(t1);
    h0 = (unsigned short)(t0 >> 16);
    h1 = (unsigned short)(t1 >> 16);
    h2 = (unsigned short)(__float_as_uint(r2) >> 16);
}

// split 8 contiguous fp32 (LDS) into three bf16x8 fragments
__device__ inline void split8(const float* ap, v8s& o0, v8s& o1, v8s& o2) {
    union { v8s v; unsigned short u[8]; } r0, r1, r2;
    float4 f0 = *(const float4*)ap;
    float4 f1 = *(const float4*)(ap + 4);
    float av[8] = {f0.x, f0.y, f0.z, f0.w, f1.x, f1.y, f1.z, f1.w};
    #pragma unroll
    for (int j = 0; j < 8; j++)
        split3(av[j], r0.u[j], r1.u[j], r2.u[j]);
    o0 = r0.v; o1 = r1.v; o2 = r2.v;
}

// ---------------------------------------------------------------------------
// K1: targets (stored transposed [d][b]) + query hash codes (packed 4x u32)
// ---------------------------------------------------------------------------
__global__ __launch_bounds__(128) void k_targets(
    const int* __restrict__ head, const int* __restrict__ rel,
    const float* __restrict__ E, const float* __restrict__ Rm,
    const float* __restrict__ proj,
    float* __restrict__ tgtT, unsigned* __restrict__ thash)
{
    __shared__ float tg[DDIM];
    int b = blockIdx.x;
    int tid = threadIdx.x;
    int h = head[b], r = rel[b];
    for (int d = tid; d < DDIM; d += 128) {
        float v = E[h*DDIM + d] * Rm[r*DDIM + d];
        tg[d] = v;
        tgtT[d*BQ + b] = v;
    }
    __syncthreads();
    int t = tid >> 5, hh = tid & 31;
    float acc = 0.f;
    #pragma unroll 8
    for (int d = 0; d < DDIM; d++)
        acc += tg[d] * proj[(t*DDIM + d)*32 + hh];
    unsigned long long m = __ballot(acc > 0.0f);
    int lane = tid & 63, w = tid >> 6;
    if (lane == 0) {
        thash[b*4 + w*2 + 0] = (unsigned)(m & 0xffffffffull);
        thash[b*4 + w*2 + 1] = (unsigned)(m >> 32);
    }
}

// ---------------------------------------------------------------------------
// K1b: build W = [proj cols | targets], 3-way split bf16 planes, layout [c][d].
// ---------------------------------------------------------------------------
__global__ __launch_bounds__(256) void k_prepw(
    const float* __restrict__ proj, const float* __restrict__ tgtT,
    unsigned short* __restrict__ Whi, unsigned short* __restrict__ Wmid,
    unsigned short* __restrict__ Wlo)
{
    int c = blockIdx.x;
    int d = threadIdx.x;   // DDIM == 256
    float x = (c < 128) ? proj[((c >> 5)*DDIM + d)*32 + (c & 31)]
                        : tgtT[d*BQ + (c - 128)];
    unsigned short h0, h1, h2;
    split3(x, h0, h1, h2);
    Whi [c*DDIM + d] = h0;
    Wmid[c*DDIM + d] = h1;
    Wlo [c*DDIM + d] = h2;
}

// ---------------------------------------------------------------------------
// K2: MFMA bf16x3 (6-product) GEMM.  out[n][c] = sum_d E[n][d] * W[c][d]
//   cols 0..127 -> sign bits packed to ahash[n][4]; cols 128..191 -> scores.
// ---------------------------------------------------------------------------
constexpr int TILE_E = 128;
constexpr int LSTR = 40;         // B plane halfword stride (32 + 8 pad)
constexpr int ASTR = 36;         // A fp32 float stride (32 + 4 pad)

__global__ __launch_bounds__(256, 2) void k_gemm(
    const float* __restrict__ E,
    const unsigned short* __restrict__ Whi, const unsigned short* __restrict__ Wmid,
    const unsigned short* __restrict__ Wlo,
    unsigned* __restrict__ ahash, float* __restrict__ scores)
{
    __shared__ __align__(16) float Af[TILE_E*ASTR];             // 18432 B
    __shared__ __align__(16) unsigned short Bhi[192*LSTR];      // 15360 B
    __shared__ __align__(16) unsigned short Bmid[192*LSTR];     // 15360 B
    __shared__ __align__(16) unsigned short Blo[192*LSTR];      // 15360 B
    unsigned short* bitsHalf = (unsigned short*)Af;             // aliased after compute

    int tid = threadIdx.x;
    int l = tid & 63, w = tid >> 6;
    int wm = w >> 1, wn = w & 1;
    int m = l & 15, quad = l >> 4;
    int n0 = blockIdx.x * TILE_E;

    v4f acc[4][6];
    #pragma unroll
    for (int a = 0; a < 4; a++)
        #pragma unroll
        for (int c = 0; c < 6; c++)
            acc[a][c] = (v4f)0.0f;

    for (int ch = 0; ch < DDIM/32; ch++) {
        int d0 = ch * 32;
        __syncthreads();
        // ---- stage A chunk fp32 (128x32) ----
        #pragma unroll
        for (int it = 0; it < 4; it++) {
            int idx = tid + it*256;         // 0..1023
            int row = idx >> 3;
            int kq  = (idx & 7) * 4;
            int n = n0 + row; if (n >= NENT) n = NENT - 1;
            *(float4*)&Af[row*ASTR + kq] = *(const float4*)(E + (size_t)n*DDIM + d0 + kq);
        }
        // ---- stage B chunk (192x32), 3 pre-split planes ----
        #pragma unroll
        for (int it = 0; it < 3; it++) {
            int idx = tid + it*256;         // 0..767
            int col = idx >> 2;
            int k8  = (idx & 3) * 8;
            *(uint4*)&Bhi [col*LSTR + k8] = *(const uint4*)(Whi  + col*DDIM + d0 + k8);
            *(uint4*)&Bmid[col*LSTR + k8] = *(const uint4*)(Wmid + col*DDIM + d0 + k8);
            *(uint4*)&Blo [col*LSTR + k8] = *(const uint4*)(Wlo  + col*DDIM + d0 + k8);
        }
        __syncthreads();
        // ---- A fragments: fp32 from LDS, split in-register ----
        v8s a0[4], a1[4], a2[4];
        #pragma unroll
        for (int a = 0; a < 4; a++)
            split8(&Af[(wm*64 + a*16 + m)*ASTR + quad*8], a0[a], a1[a], a2[a]);
        // ---- 6-product MFMA ----
        #pragma unroll
        for (int c = 0; c < 6; c++) {
            int co = (wn*96 + c*16 + m)*LSTR + quad*8;
            v8s b0 = *(const v8s*)&Bhi [co];
            v8s b1 = *(const v8s*)&Bmid[co];
            v8s b2 = *(const v8s*)&Blo [co];
            #pragma unroll
            for (int a = 0; a < 4; a++) {
                acc[a][c] = __builtin_amdgcn_mfma_f32_16x16x32_bf16(a2[a], b0, acc[a][c], 0, 0, 0);
                acc[a][c] = __builtin_amdgcn_mfma_f32_16x16x32_bf16(a0[a], b2, acc[a][c], 0, 0, 0);
                acc[a][c] = __builtin_amdgcn_mfma_f32_16x16x32_bf16(a1[a], b1, acc[a][c], 0, 0, 0);
                acc[a][c] = __builtin_amdgcn_mfma_f32_16x16x32_bf16(a1[a], b0, acc[a][c], 0, 0, 0);
                acc[a][c] = __builtin_amdgcn_mfma_f32_16x16x32_bf16(a0[a], b1, acc[a][c], 0, 0, 0);
                acc[a][c] = __builtin_amdgcn_mfma_f32_16x16x32_bf16(a0[a], b0, acc[a][c], 0, 0, 0);
            }
        }
    }

    __syncthreads();   // protect Af before bitsHalf aliasing
    // ---- epilogue: C/D layout col=lane&15, row=quad*4+reg ----
    #pragma unroll
    for (int c = 0; c < 6; c++) {
        int ct = wn*6 + c;                 // global col-tile 0..11
        if (ct < 8) {
            #pragma unroll
            for (int a = 0; a < 4; a++) {
                #pragma unroll
                for (int r = 0; r < 4; r++) {
                    unsigned long long mb = __ballot(acc[a][c][r] > 0.0f);
                    if (m == 0) {
                        int rowl = wm*64 + a*16 + quad*4 + r;
                        bitsHalf[rowl*8 + ct] = (unsigned short)(mb >> (quad*16));
                    }
                }
            }
        } else {
            int b = ct*16 - 128 + m;       // query index 0..63
            #pragma unroll
            for (int a = 0; a < 4; a++) {
                int nb = n0 + wm*64 + a*16 + quad*4;
                if (nb < NENT)
                    *(float4*)(scores + (size_t)b*NENT + nb) = *(float4*)&acc[a][c];
            }
        }
    }
    __syncthreads();
    if (tid < TILE_E) {
        int n = n0 + tid;
        if (n < NENT)
            *(uint4*)(ahash + (size_t)n*4) = *(const uint4*)&bitsHalf[tid*8];
    }
}

// ---------------------------------------------------------------------------
// K3a: per-(query,slice) distance bytes + slice histogram.
// ---------------------------------------------------------------------------
__global__ __launch_bounds__(256) void k_dist(
    const unsigned* __restrict__ ahash, const unsigned* __restrict__ thash,
    unsigned char* __restrict__ dist8, unsigned short* __restrict__ histG)
{
    __shared__ unsigned hist[HPAD];
    int s = blockIdx.x, b = blockIdx.y, tid = threadIdx.x;
    for (int i = tid; i < HPAD; i += 256) hist[i] = 0u;
    uint4 tw = *(const uint4*)(thash + b*4);
    __syncthreads();
    int n0 = s*SLICE;
    int n1 = n0 + SLICE; if (n1 > NENT) n1 = NENT;
    unsigned char* drow = dist8 + (size_t)b*NENT;
    for (int n = n0 + tid*4; n < n1; n += 1024) {
        int dv[4];
        #pragma unroll
        for (int i = 0; i < 4; i++) {
            uint4 a = *(const uint4*)(ahash + (size_t)(n+i)*4);
            dv[i] = __popc(a.x^tw.x) + __popc(a.y^tw.y) +
                    __popc(a.z^tw.z) + __popc(a.w^tw.w);
            atomicAdd(&hist[dv[i]], 1u);
        }
        uchar4 o = make_uchar4((unsigned char)dv[0], (unsigned char)dv[1],
                               (unsigned char)dv[2], (unsigned char)dv[3]);
        *(uchar4*)(drow + n) = o;
    }
    __syncthreads();
    unsigned short* hrow = histG + ((size_t)b*NSLICE + s)*HPAD;
    for (int i = tid; i < 129; i += 256) hrow[i] = (unsigned short)hist[i];
}

// ---------------------------------------------------------------------------
// K3b: per-query: total histogram -> d*, quota R; slice prefix -> nCut.
// ---------------------------------------------------------------------------
__global__ __launch_bounds__(64) void k_cut(
    const unsigned char* __restrict__ dist8, const unsigned short* __restrict__ histG,
    int* __restrict__ dsG, int* __restrict__ ncG)
{
    __shared__ unsigned histT[HPAD];
    __shared__ int dsS, slS, rpS;
    int b = blockIdx.x, tid = threadIdx.x;
    for (int d = tid; d < 129; d += 64) {
        unsigned sum = 0;
        for (int s = 0; s < NSLICE; s++)
            sum += histG[((size_t)b*NSLICE + s)*HPAD + d];
        histT[d] = sum;
    }
    __syncthreads();
    if (tid == 0) {
        unsigned cum = 0; int ds = 128; unsigned R = 1;
        for (int d = 0; d < 129; d++) {
            unsigned c = cum + histT[d];
            if (c >= (unsigned)CANDN) { ds = d; R = (unsigned)CANDN - cum; break; }
            cum = c;
        }
        dsS = ds; dsG[b] = ds;
        unsigned acc = 0;
        for (int s = 0; s < NSLICE; s++) {
            unsigned c = histG[((size_t)b*NSLICE + s)*HPAD + ds];
            if (acc + c >= R) { slS = s; rpS = (int)(R - acc); break; }
            acc += c;
        }
    }
    __syncthreads();
    int ds = dsS;
    unsigned Rp = (unsigned)rpS;
    const unsigned char* drow = dist8 + (size_t)b*NENT;
    int sBase = slS*SLICE;
    int sEnd = sBase + SLICE; if (sEnd > NENT) sEnd = NENT;
    unsigned cnt = 0;
    for (int base = sBase; base < sEnd; base += 64) {
        int n = base + tid;
        bool eq = (n < sEnd) && (drow[n] == (unsigned char)ds);
        unsigned long long mm = __ballot(eq);
        unsigned c = __popcll(mm);
        if (cnt + c >= Rp) {
            unsigned pre = __popcll(mm & ((1ull << tid) - 1ull));
            if (eq && (cnt + pre + 1u == Rp)) ncG[b] = n;
            break;
        }
        cnt += c;
    }
}

// ---------------------------------------------------------------------------
// K4a: per-(query, slice) single-pass top-10 pool builder + EXACT fp32
// rescore of the 10 slice winners (sequential-d order, matches reference).
// ---------------------------------------------------------------------------
__global__ __launch_bounds__(256) void k_part(
    const unsigned char* __restrict__ dist8, const float* __restrict__ scores,
    const int* __restrict__ dsG, const int* __restrict__ ncG,
    const float* __restrict__ tgtT, const float* __restrict__ E,
    float* __restrict__ partS, int* __restrict__ partI)
{
    __shared__ float rs[256];
    __shared__ int   ri[256];
    __shared__ int   rt[256];
    __shared__ int   chosenI[KTOP];
    __shared__ float tgl[DDIM];

    int sl = blockIdx.x, b = blockIdx.y, tid = threadIdx.x;
    int ds = dsG[b], nc = ncG[b];
    const unsigned char* drow = dist8 + (size_t)b*NENT;
    const float* srow = scores + (size_t)b*NENT;
    int n0 = sl*SLICE;
    int n1 = n0 + SLICE; if (n1 > NENT) n1 = NENT;

    float topS[KTOP]; int topI[KTOP];
    #pragma unroll
    for (int i = 0; i < KTOP; i++) { topS[i] = -FLT_MAX; topI[i] = 0x7fffffff; }

    for (int n = n0 + tid*4; n < n1; n += 1024) {
        uchar4 dv = *(const uchar4*)(drow + n);
        unsigned char da[4] = {dv.x, dv.y, dv.z, dv.w};
        #pragma unroll
        for (int i = 0; i < 4; i++) {
            int d = da[i];
            int nn = n + i;
            if (d < ds || (d == ds && nn <= nc)) {
                float sc = srow[nn];
                if (sc > topS[KTOP-1]) {
                    int p = KTOP - 1;
                    while (p > 0 && topS[p-1] < sc) {
                        topS[p] = topS[p-1]; topI[p] = topI[p-1]; p--;
                    }
                    topS[p] = sc; topI[p] = nn;
                }
            }
        }
    }

    // tournament: extract slice top-10 (by approx score) into chosenI
    int ph = 0;
    for (int r = 0; r < KTOP; r++) {
        rs[tid] = topS[ph]; ri[tid] = topI[ph]; rt[tid] = tid;
        __syncthreads();
        for (int st = 128; st > 0; st >>= 1) {
            if (tid < st) {
                bool take = (rs[tid+st] > rs[tid]) ||
                            (rs[tid+st] == rs[tid] && ri[tid+st] < ri[tid]);
                if (take) { rs[tid]=rs[tid+st]; ri[tid]=ri[tid+st]; rt[tid]=rt[tid+st]; }
            }
            __syncthreads();
        }
        if (tid == 0) {
            chosenI[r] = ri[0];
            partI[((size_t)b*NSLICE + sl)*KTOP + r] = ri[0];
        }
        int winner = rt[0];
        __syncthreads();
        if (tid == winner) ph++;
        __syncthreads();
    }

    // exact fp32 rescore of the 10 winners (order-preserving sequential dot)
    for (int d = tid; d < DDIM; d += 256) tgl[d] = tgtT[d*BQ + b];
    __syncthreads();
    if (tid < KTOP) {
        int idx = chosenI[tid];
        float sc = -FLT_MAX;
        if (idx >= 0 && idx < NENT) {
            const float* er = E + (size_t)idx*DDIM;
            float acc = 0.f;
            #pragma unroll 8
            for (int d = 0; d < DDIM; d += 4) {
                float4 v = *(const float4*)(er + d);
                acc += v.x*tgl[d+0];
                acc += v.y*tgl[d+1];
                acc += v.z*tgl[d+2];
                acc += v.w*tgl[d+3];
            }
            sc = acc;
        }
        partS[((size_t)b*NSLICE + sl)*KTOP + tid] = sc;
    }
}

// ---------------------------------------------------------------------------
// K4b: final top-10 over the 160-entry exact-scored pool (argmax w/ used[]).
// ---------------------------------------------------------------------------
__global__ __launch_bounds__(256) void k_merge(
    const float* __restrict__ partS, const int* __restrict__ partI,
    float* __restrict__ out)
{
    __shared__ float sc2[NSLICE*KTOP];
    __shared__ int   ix2[NSLICE*KTOP];
    int b = blockIdx.x, tid = threadIdx.x;
    if (tid < NSLICE*KTOP) {
        sc2[tid] = partS[(size_t)b*NSLICE*KTOP + tid];
        ix2[tid] = partI[(size_t)b*NSLICE*KTOP + tid];
    }
    __syncthreads();
    if (tid == 0) {
        bool used[NSLICE*KTOP];
        for (int i = 0; i < NSLICE*KTOP; i++) used[i] = false;
        for (int r = 0; r < KTOP; r++) {
            float bs = -FLT_MAX; int bi = 0x7fffffff; int bp = 0;
            for (int i = 0; i < NSLICE*KTOP; i++) {
                if (!used[i]) {
                    float v = sc2[i]; int id = ix2[i];
                    if (v > bs || (v == bs && id < bi)) { bs = v; bi = id; bp = i; }
                }
            }
            used[bp] = true;
            out[b*KTOP + r]           = (float)bi;
            out[BQ*KTOP + b*KTOP + r] = bs;
        }
    }
}

// ---------------------------------------------------------------------------
extern "C" void kernel_launch(void* const* d_in, const int* in_sizes, int n_in,
                              void* d_out, int out_size, void* d_ws, size_t ws_size,
                              hipStream_t stream)
{
    const int*   head = (const int*)d_in[0];
    const int*   rel  = (const int*)d_in[1];
    const float* E    = (const float*)d_in[2];
    const float* Rm   = (const float*)d_in[3];
    const float* proj = (const float*)d_in[4];
    // d_in[5] = k (always 10)

    char* ws = (char*)d_ws;
    float*          tgtT   = (float*)(ws);                    // 65536 B
    unsigned*       thash  = (unsigned*)(ws + 65536);         // 1024 B
    unsigned*       ahash  = (unsigned*)(ws + 66560);         // 1.6 MB
    float*          scores = (float*)(ws + 1666560);          // 25.6 MB
    unsigned char*  dist8  = (unsigned char*)(ws + 27266560); // 6.4 MB
    int*            dsG    = (int*)(ws + 33666560);           // 256 B
    int*            ncG    = (int*)(ws + 33666816);           // 256 B
    float*          partS  = (float*)(ws + 33667072);         // 40960 B
    int*            partI  = (int*)(ws + 33708032);           // 40960 B
    unsigned short* histG  = (unsigned short*)(ws + 33748992);// 270336 B
    unsigned short* Whi    = (unsigned short*)(ws + 34019328);// 98304 B
    unsigned short* Wmid   = (unsigned short*)(ws + 34117632);// 98304 B
    unsigned short* Wlo    = (unsigned short*)(ws + 34215936);// 98304 B
    float*          out    = (float*)d_out;

    hipLaunchKernelGGL(k_targets, dim3(BQ), dim3(128), 0, stream,
                       head, rel, E, Rm, proj, tgtT, thash);
    hipLaunchKernelGGL(k_prepw, dim3(192), dim3(256), 0, stream,
                       proj, tgtT, Whi, Wmid, Wlo);
    hipLaunchKernelGGL(k_gemm, dim3((NENT + TILE_E - 1)/TILE_E), dim3(256), 0, stream,
                       E, Whi, Wmid, Wlo, ahash, scores);
    hipLaunchKernelGGL(k_dist, dim3(NSLICE, BQ), dim3(256), 0, stream,
                       ahash, thash, dist8, histG);
    hipLaunchKernelGGL(k_cut, dim3(BQ), dim3(64), 0, stream,
                       dist8, histG, dsG, ncG);
    hipLaunchKernelGGL(k_part, dim3(NSLICE, BQ), dim3(256), 0, stream,
                       dist8, scores, dsG, ncG, tgtT, E, partS, partI);
    hipLaunchKernelGGL(k_merge, dim3(BQ), dim3(256), 0, stream,
                       partS, partI, out);
}

// Round 8
// 357.294 us; speedup vs baseline: 1.6544x; 1.6434x over previous
//
#include <hip/hip_runtime.h>
#include <hip/hip_bf16.h>
#include <float.h>

// Problem constants (fixed by the reference)
constexpr int NENT  = 100000;
constexpr int DDIM  = 256;
constexpr int BQ    = 64;
constexpr int CANDN = 10000;
constexpr int KTOP  = 10;
constexpr int NSLICE = 16;
constexpr int SLICE  = 6272;    // 16*6272 = 100352 >= NENT, multiple of 4
constexpr int HPAD   = 132;     // histG per-(b,s) stride

typedef short v8s __attribute__((ext_vector_type(8)));   // 8 bf16 (4 VGPRs)
typedef float v4f __attribute__((ext_vector_type(4)));   // MFMA accumulator

// 3-way split: x ~= b0 + b1 + b2 (bf16 each), residual ~2^-21 |x|
__device__ inline void split3(float x, unsigned short& h0, unsigned short& h1,
                              unsigned short& h2) {
    unsigned t0 = __float_as_uint(x) & 0xffff0000u;
    float r1 = x - __uint_as_float(t0);
    unsigned t1 = __float_as_uint(r1) & 0xffff0000u;
    float r2 = r1 - __uint_as_float(t1);
    h0 = (unsigned short)(t0 >> 16);
    h1 = (unsigned short)(t1 >> 16);
    h2 = (unsigned short)(__float_as_uint(r2) >> 16);
}

// split 8 contiguous fp32 (LDS) into three bf16x8 fragments
__device__ inline void split8(const float* ap, v8s& o0, v8s& o1, v8s& o2) {
    union { v8s v; unsigned short u[8]; } r0, r1, r2;
    float4 f0 = *(const float4*)ap;
    float4 f1 = *(const float4*)(ap + 4);
    float av[8] = {f0.x, f0.y, f0.z, f0.w, f1.x, f1.y, f1.z, f1.w};
    #pragma unroll
    for (int j = 0; j < 8; j++)
        split3(av[j], r0.u[j], r1.u[j], r2.u[j]);
    o0 = r0.v; o1 = r1.v; o2 = r2.v;
}

// ---------------------------------------------------------------------------
// K1: targets (stored transposed [d][b]) + query hash codes (packed 4x u32)
// ---------------------------------------------------------------------------
__global__ __launch_bounds__(128) void k_targets(
    const int* __restrict__ head, const int* __restrict__ rel,
    const float* __restrict__ E, const float* __restrict__ Rm,
    const float* __restrict__ proj,
    float* __restrict__ tgtT, unsigned* __restrict__ thash)
{
    __shared__ float tg[DDIM];
    int b = blockIdx.x;
    int tid = threadIdx.x;
    int h = head[b], r = rel[b];
    for (int d = tid; d < DDIM; d += 128) {
        float v = E[h*DDIM + d] * Rm[r*DDIM + d];
        tg[d] = v;
        tgtT[d*BQ + b] = v;
    }
    __syncthreads();
    int t = tid >> 5, hh = tid & 31;
    float acc = 0.f;
    #pragma unroll 8
    for (int d = 0; d < DDIM; d++)
        acc += tg[d] * proj[(t*DDIM + d)*32 + hh];
    unsigned long long m = __ballot(acc > 0.0f);
    int lane = tid & 63, w = tid >> 6;
    if (lane == 0) {
        thash[b*4 + w*2 + 0] = (unsigned)(m & 0xffffffffull);
        thash[b*4 + w*2 + 1] = (unsigned)(m >> 32);
    }
}

// ---------------------------------------------------------------------------
// K1b: build W = [proj cols | targets], 3-way split bf16 planes, layout [c][d].
// ---------------------------------------------------------------------------
__global__ __launch_bounds__(256) void k_prepw(
    const float* __restrict__ proj, const float* __restrict__ tgtT,
    unsigned short* __restrict__ Whi, unsigned short* __restrict__ Wmid,
    unsigned short* __restrict__ Wlo)
{
    int c = blockIdx.x;
    int d = threadIdx.x;   // DDIM == 256
    float x = (c < 128) ? proj[((c >> 5)*DDIM + d)*32 + (c & 31)]
                        : tgtT[d*BQ + (c - 128)];
    unsigned short h0, h1, h2;
    split3(x, h0, h1, h2);
    Whi [c*DDIM + d] = h0;
    Wmid[c*DDIM + d] = h1;
    Wlo [c*DDIM + d] = h2;
}

// ---------------------------------------------------------------------------
// K2: MFMA bf16x3 (6-product) GEMM.  out[n][c] = sum_d E[n][d] * W[c][d]
//   cols 0..127 -> sign bits packed to ahash[n][4]; cols 128..191 -> scores.
// ---------------------------------------------------------------------------
constexpr int TILE_E = 128;
constexpr int LSTR = 40;         // B plane halfword stride (32 + 8 pad)
constexpr int ASTR = 36;         // A fp32 float stride (32 + 4 pad)

__global__ __launch_bounds__(256, 2) void k_gemm(
    const float* __restrict__ E,
    const unsigned short* __restrict__ Whi, const unsigned short* __restrict__ Wmid,
    const unsigned short* __restrict__ Wlo,
    unsigned* __restrict__ ahash, float* __restrict__ scores)
{
    __shared__ __align__(16) float Af[TILE_E*ASTR];             // 18432 B
    __shared__ __align__(16) unsigned short Bhi[192*LSTR];      // 15360 B
    __shared__ __align__(16) unsigned short Bmid[192*LSTR];     // 15360 B
    __shared__ __align__(16) unsigned short Blo[192*LSTR];      // 15360 B
    unsigned short* bitsHalf = (unsigned short*)Af;             // aliased after compute

    int tid = threadIdx.x;
    int l = tid & 63, w = tid >> 6;
    int wm = w >> 1, wn = w & 1;
    int m = l & 15, quad = l >> 4;
    int n0 = blockIdx.x * TILE_E;

    v4f acc[4][6];
    #pragma unroll
    for (int a = 0; a < 4; a++)
        #pragma unroll
        for (int c = 0; c < 6; c++)
            acc[a][c] = (v4f)0.0f;

    for (int ch = 0; ch < DDIM/32; ch++) {
        int d0 = ch * 32;
        __syncthreads();
        // ---- stage A chunk fp32 (128x32) ----
        #pragma unroll
        for (int it = 0; it < 4; it++) {
            int idx = tid + it*256;         // 0..1023
            int row = idx >> 3;
            int kq  = (idx & 7) * 4;
            int n = n0 + row; if (n >= NENT) n = NENT - 1;
            *(float4*)&Af[row*ASTR + kq] = *(const float4*)(E + (size_t)n*DDIM + d0 + kq);
        }
        // ---- stage B chunk (192x32), 3 pre-split planes ----
        #pragma unroll
        for (int it = 0; it < 3; it++) {
            int idx = tid + it*256;         // 0..767
            int col = idx >> 2;
            int k8  = (idx & 3) * 8;
            *(uint4*)&Bhi [col*LSTR + k8] = *(const uint4*)(Whi  + col*DDIM + d0 + k8);
            *(uint4*)&Bmid[col*LSTR + k8] = *(const uint4*)(Wmid + col*DDIM + d0 + k8);
            *(uint4*)&Blo [col*LSTR + k8] = *(const uint4*)(Wlo  + col*DDIM + d0 + k8);
        }
        __syncthreads();
        // ---- A fragments: fp32 from LDS, split in-register ----
        v8s a0[4], a1[4], a2[4];
        #pragma unroll
        for (int a = 0; a < 4; a++)
            split8(&Af[(wm*64 + a*16 + m)*ASTR + quad*8], a0[a], a1[a], a2[a]);
        // ---- 6-product MFMA ----
        #pragma unroll
        for (int c = 0; c < 6; c++) {
            int co = (wn*96 + c*16 + m)*LSTR + quad*8;
            v8s b0 = *(const v8s*)&Bhi [co];
            v8s b1 = *(const v8s*)&Bmid[co];
            v8s b2 = *(const v8s*)&Blo [co];
            #pragma unroll
            for (int a = 0; a < 4; a++) {
                acc[a][c] = __builtin_amdgcn_mfma_f32_16x16x32_bf16(a2[a], b0, acc[a][c], 0, 0, 0);
                acc[a][c] = __builtin_amdgcn_mfma_f32_16x16x32_bf16(a0[a], b2, acc[a][c], 0, 0, 0);
                acc[a][c] = __builtin_amdgcn_mfma_f32_16x16x32_bf16(a1[a], b1, acc[a][c], 0, 0, 0);
                acc[a][c] = __builtin_amdgcn_mfma_f32_16x16x32_bf16(a1[a], b0, acc[a][c], 0, 0, 0);
                acc[a][c] = __builtin_amdgcn_mfma_f32_16x16x32_bf16(a0[a], b1, acc[a][c], 0, 0, 0);
                acc[a][c] = __builtin_amdgcn_mfma_f32_16x16x32_bf16(a0[a], b0, acc[a][c], 0, 0, 0);
            }
        }
    }

    __syncthreads();   // protect Af before bitsHalf aliasing
    // ---- epilogue: C/D layout col=lane&15, row=quad*4+reg ----
    #pragma unroll
    for (int c = 0; c < 6; c++) {
        int ct = wn*6 + c;                 // global col-tile 0..11
        if (ct < 8) {
            #pragma unroll
            for (int a = 0; a < 4; a++) {
                #pragma unroll
                for (int r = 0; r < 4; r++) {
                    unsigned long long mb = __ballot(acc[a][c][r] > 0.0f);
                    if (m == 0) {
                        int rowl = wm*64 + a*16 + quad*4 + r;
                        bitsHalf[rowl*8 + ct] = (unsigned short)(mb >> (quad*16));
                    }
                }
            }
        } else {
            int b = ct*16 - 128 + m;       // query index 0..63
            #pragma unroll
            for (int a = 0; a < 4; a++) {
                int nb = n0 + wm*64 + a*16 + quad*4;
                if (nb < NENT)
                    *(float4*)(scores + (size_t)b*NENT + nb) = *(float4*)&acc[a][c];
            }
        }
    }
    __syncthreads();
    if (tid < TILE_E) {
        int n = n0 + tid;
        if (n < NENT)
            *(uint4*)(ahash + (size_t)n*4) = *(const uint4*)&bitsHalf[tid*8];
    }
}

// ---------------------------------------------------------------------------
// K3a: per-(query,slice) distance bytes + slice histogram.
// ---------------------------------------------------------------------------
__global__ __launch_bounds__(256) void k_dist(
    const unsigned* __restrict__ ahash, const unsigned* __restrict__ thash,
    unsigned char* __restrict__ dist8, unsigned short* __restrict__ histG)
{
    __shared__ unsigned hist[HPAD];
    int s = blockIdx.x, b = blockIdx.y, tid = threadIdx.x;
    for (int i = tid; i < HPAD; i += 256) hist[i] = 0u;
    uint4 tw = *(const uint4*)(thash + b*4);
    __syncthreads();
    int n0 = s*SLICE;
    int n1 = n0 + SLICE; if (n1 > NENT) n1 = NENT;
    unsigned char* drow = dist8 + (size_t)b*NENT;
    for (int n = n0 + tid*4; n < n1; n += 1024) {
        int dv[4];
        #pragma unroll
        for (int i = 0; i < 4; i++) {
            uint4 a = *(const uint4*)(ahash + (size_t)(n+i)*4);
            dv[i] = __popc(a.x^tw.x) + __popc(a.y^tw.y) +
                    __popc(a.z^tw.z) + __popc(a.w^tw.w);
            atomicAdd(&hist[dv[i]], 1u);
        }
        uchar4 o = make_uchar4((unsigned char)dv[0], (unsigned char)dv[1],
                               (unsigned char)dv[2], (unsigned char)dv[3]);
        *(uchar4*)(drow + n) = o;
    }
    __syncthreads();
    unsigned short* hrow = histG + ((size_t)b*NSLICE + s)*HPAD;
    for (int i = tid; i < 129; i += 256) hrow[i] = (unsigned short)hist[i];
}

// ---------------------------------------------------------------------------
// K3b: per-query: total histogram -> d*, quota R; slice prefix -> nCut.
// ---------------------------------------------------------------------------
__global__ __launch_bounds__(64) void k_cut(
    const unsigned char* __restrict__ dist8, const unsigned short* __restrict__ histG,
    int* __restrict__ dsG, int* __restrict__ ncG)
{
    __shared__ unsigned histT[HPAD];
    __shared__ int dsS, slS, rpS;
    int b = blockIdx.x, tid = threadIdx.x;
    for (int d = tid; d < 129; d += 64) {
        unsigned sum = 0;
        for (int s = 0; s < NSLICE; s++)
            sum += histG[((size_t)b*NSLICE + s)*HPAD + d];
        histT[d] = sum;
    }
    __syncthreads();
    if (tid == 0) {
        unsigned cum = 0; int ds = 128; unsigned R = 1;
        for (int d = 0; d < 129; d++) {
            unsigned c = cum + histT[d];
            if (c >= (unsigned)CANDN) { ds = d; R = (unsigned)CANDN - cum; break; }
            cum = c;
        }
        dsS = ds; dsG[b] = ds;
        unsigned acc = 0;
        for (int s = 0; s < NSLICE; s++) {
            unsigned c = histG[((size_t)b*NSLICE + s)*HPAD + ds];
            if (acc + c >= R) { slS = s; rpS = (int)(R - acc); break; }
            acc += c;
        }
    }
    __syncthreads();
    int ds = dsS;
    unsigned Rp = (unsigned)rpS;
    const unsigned char* drow = dist8 + (size_t)b*NENT;
    int sBase = slS*SLICE;
    int sEnd = sBase + SLICE; if (sEnd > NENT) sEnd = NENT;
    unsigned cnt = 0;
    for (int base = sBase; base < sEnd; base += 64) {
        int n = base + tid;
        bool eq = (n < sEnd) && (drow[n] == (unsigned char)ds);
        unsigned long long mm = __ballot(eq);
        unsigned c = __popcll(mm);
        if (cnt + c >= Rp) {
            unsigned pre = __popcll(mm & ((1ull << tid) - 1ull));
            if (eq && (cnt + pre + 1u == Rp)) ncG[b] = n;
            break;
        }
        cnt += c;
    }
}

// ---------------------------------------------------------------------------
// K4a: per-(query, slice) single-pass top-10 pool builder + EXACT fp32
// rescore of the 10 slice winners (sequential-d order, matches reference).
// ---------------------------------------------------------------------------
__global__ __launch_bounds__(256) void k_part(
    const unsigned char* __restrict__ dist8, const float* __restrict__ scores,
    const int* __restrict__ dsG, const int* __restrict__ ncG,
    const float* __restrict__ tgtT, const float* __restrict__ E,
    float* __restrict__ partS, int* __restrict__ partI)
{
    __shared__ float rs[256];
    __shared__ int   ri[256];
    __shared__ int   rt[256];
    __shared__ int   chosenI[KTOP];
    __shared__ float tgl[DDIM];

    int sl = blockIdx.x, b = blockIdx.y, tid = threadIdx.x;
    int ds = dsG[b], nc = ncG[b];
    const unsigned char* drow = dist8 + (size_t)b*NENT;
    const float* srow = scores + (size_t)b*NENT;
    int n0 = sl*SLICE;
    int n1 = n0 + SLICE; if (n1 > NENT) n1 = NENT;

    float topS[KTOP]; int topI[KTOP];
    #pragma unroll
    for (int i = 0; i < KTOP; i++) { topS[i] = -FLT_MAX; topI[i] = 0x7fffffff; }

    for (int n = n0 + tid*4; n < n1; n += 1024) {
        uchar4 dv = *(const uchar4*)(drow + n);
        unsigned char da[4] = {dv.x, dv.y, dv.z, dv.w};
        #pragma unroll
        for (int i = 0; i < 4; i++) {
            int d = da[i];
            int nn = n + i;
            if (d < ds || (d == ds && nn <= nc)) {
                float sc = srow[nn];
                if (sc > topS[KTOP-1]) {
                    int p = KTOP - 1;
                    while (p > 0 && topS[p-1] < sc) {
                        topS[p] = topS[p-1]; topI[p] = topI[p-1]; p--;
                    }
                    topS[p] = sc; topI[p] = nn;
                }
            }
        }
    }

    // tournament: extract slice top-10 (by approx score) into chosenI
    int ph = 0;
    for (int r = 0; r < KTOP; r++) {
        rs[tid] = topS[ph]; ri[tid] = topI[ph]; rt[tid] = tid;
        __syncthreads();
        for (int st = 128; st > 0; st >>= 1) {
            if (tid < st) {
                bool take = (rs[tid+st] > rs[tid]) ||
                            (rs[tid+st] == rs[tid] && ri[tid+st] < ri[tid]);
                if (take) { rs[tid]=rs[tid+st]; ri[tid]=ri[tid+st]; rt[tid]=rt[tid+st]; }
            }
            __syncthreads();
        }
        if (tid == 0) {
            chosenI[r] = ri[0];
            partI[((size_t)b*NSLICE + sl)*KTOP + r] = ri[0];
        }
        int winner = rt[0];
        __syncthreads();
        if (tid == winner) ph++;
        __syncthreads();
    }

    // exact fp32 rescore of the 10 winners (order-preserving sequential dot)
    for (int d = tid; d < DDIM; d += 256) tgl[d] = tgtT[d*BQ + b];
    __syncthreads();
    if (tid < KTOP) {
        int idx = chosenI[tid];
        float sc = -FLT_MAX;
        if (idx >= 0 && idx < NENT) {
            const float* er = E + (size_t)idx*DDIM;
            float acc = 0.f;
            #pragma unroll 8
            for (int d = 0; d < DDIM; d += 4) {
                float4 v = *(const float4*)(er + d);
                acc += v.x*tgl[d+0];
                acc += v.y*tgl[d+1];
                acc += v.z*tgl[d+2];
                acc += v.w*tgl[d+3];
            }
            sc = acc;
        }
        partS[((size_t)b*NSLICE + sl)*KTOP + tid] = sc;
    }
}

// ---------------------------------------------------------------------------
// K4b: final top-10 via PARALLEL rank computation over the 160-entry pool.
// Each thread owns one pool entry, counts how many entries beat it
// (score desc, entity-index asc, pool-position asc). rank<10 -> scatter out.
// Pool entity indices are distinct (disjoint slices), so ranks are unique.
// ---------------------------------------------------------------------------
__global__ __launch_bounds__(256) void k_merge(
    const float* __restrict__ partS, const int* __restrict__ partI,
    float* __restrict__ out)
{
    __shared__ float sc2[NSLICE*KTOP];
    __shared__ int   ix2[NSLICE*KTOP];
    int b = blockIdx.x, tid = threadIdx.x;
    if (tid < NSLICE*KTOP) {
        sc2[tid] = partS[(size_t)b*NSLICE*KTOP + tid];
        ix2[tid] = partI[(size_t)b*NSLICE*KTOP + tid];
    }
    __syncthreads();
    if (tid < NSLICE*KTOP) {
        float mv = sc2[tid]; int mi = ix2[tid];
        int rank = 0;
        #pragma unroll 8
        for (int i = 0; i < NSLICE*KTOP; i++) {
            float v = sc2[i]; int id = ix2[i];
            bool beats = (v > mv) ||
                         (v == mv && (id < mi || (id == mi && i < tid)));
            rank += beats ? 1 : 0;
        }
        if (rank < KTOP) {
            out[b*KTOP + rank]           = (float)mi;
            out[BQ*KTOP + b*KTOP + rank] = mv;
        }
    }
}

// ---------------------------------------------------------------------------
extern "C" void kernel_launch(void* const* d_in, const int* in_sizes, int n_in,
                              void* d_out, int out_size, void* d_ws, size_t ws_size,
                              hipStream_t stream)
{
    const int*   head = (const int*)d_in[0];
    const int*   rel  = (const int*)d_in[1];
    const float* E    = (const float*)d_in[2];
    const float* Rm   = (const float*)d_in[3];
    const float* proj = (const float*)d_in[4];
    // d_in[5] = k (always 10)

    char* ws = (char*)d_ws;
    float*          tgtT   = (float*)(ws);                    // 65536 B
    unsigned*       thash  = (unsigned*)(ws + 65536);         // 1024 B
    unsigned*       ahash  = (unsigned*)(ws + 66560);         // 1.6 MB
    float*          scores = (float*)(ws + 1666560);          // 25.6 MB
    unsigned char*  dist8  = (unsigned char*)(ws + 27266560); // 6.4 MB
    int*            dsG    = (int*)(ws + 33666560);           // 256 B
    int*            ncG    = (int*)(ws + 33666816);           // 256 B
    float*          partS  = (float*)(ws + 33667072);         // 40960 B
    int*            partI  = (int*)(ws + 33708032);           // 40960 B
    unsigned short* histG  = (unsigned short*)(ws + 33748992);// 270336 B
    unsigned short* Whi    = (unsigned short*)(ws + 34019328);// 98304 B
    unsigned short* Wmid   = (unsigned short*)(ws + 34117632);// 98304 B
    unsigned short* Wlo    = (unsigned short*)(ws + 34215936);// 98304 B
    float*          out    = (float*)d_out;

    hipLaunchKernelGGL(k_targets, dim3(BQ), dim3(128), 0, stream,
                       head, rel, E, Rm, proj, tgtT, thash);
    hipLaunchKernelGGL(k_prepw, dim3(192), dim3(256), 0, stream,
                       proj, tgtT, Whi, Wmid, Wlo);
    hipLaunchKernelGGL(k_gemm, dim3((NENT + TILE_E - 1)/TILE_E), dim3(256), 0, stream,
                       E, Whi, Wmid, Wlo, ahash, scores);
    hipLaunchKernelGGL(k_dist, dim3(NSLICE, BQ), dim3(256), 0, stream,
                       ahash, thash, dist8, histG);
    hipLaunchKernelGGL(k_cut, dim3(BQ), dim3(64), 0, stream,
                       dist8, histG, dsG, ncG);
    hipLaunchKernelGGL(k_part, dim3(NSLICE, BQ), dim3(256), 0, stream,
                       dist8, scores, dsG, ncG, tgtT, E, partS, partI);
    hipLaunchKernelGGL(k_merge, dim3(BQ), dim3(256), 0, stream,
                       partS, partI, out);
}